// Round 14
// baseline (175.308 us; speedup 1.0000x reference)
//
#include <hip/hip_runtime.h>
#include <cstddef>

#define NCOLS 985
#define TROWS 8
#define TILEF (TROWS * NCOLS)     // 7880 floats = 31520 B (16B-aligned tiles; 7880 % 4 == 0)
#define NUNIT (TILEF / 4)         // 1970 float4 units per tile
#define GSTR  176                 // per-row factor slots
#define GTOT  (TROWS * GSTR)      // 1408
#define MAXSTR 192                // straddle-unit capacity (actual ~144)

__global__ __launch_bounds__(256) void sindy_kernel(const float* __restrict__ z,
                                                    const float* __restrict__ dz,
                                                    float* __restrict__ out, int batch,
                                                    int ntiles) {
  __shared__ alignas(16) float buf[2][TILEF];      // 63040 B (also reused for init tables)
  __shared__ float Gsh[GTOT];                      // 5632 B: 8 rows x 176 factors
  __shared__ alignas(16) unsigned int sel[MAXSTR * 4];  // straddle per-elem entries
  __shared__ unsigned short sdst[MAXSTR];          // straddle unit ids
  __shared__ unsigned short ptab[136];             // pair p -> i | j<<4
  __shared__ int cnt[2];

  const int tid = threadIdx.x;
  const int w = tid >> 6, l = tid & 63;

  // ================= init (once per block; tables live in reused buf) =========
  unsigned int* etab  = (unsigned int*)buf[0];     // [TILEF] elem -> goff | midx<<16
  uint2*        nlist = (uint2*)buf[1];            // [<=2048] normal units

  if (tid < 2) cnt[tid] = 0;
  for (int e = tid; e < 136; e += 256) {
    int p = e, i = 0; while (p >= 16 - i) { p -= 16 - i; ++i; }
    ptab[e] = (unsigned short)(i | ((i + p) << 4));
  }
  for (int fe = tid; fe < TILEF; fe += 256) {
    const int r = fe / NCOLS;
    const int c = fe - r * NCOLS;
    unsigned goff, midx;
    if (c < 153)      { goff = (unsigned)c; midx = 0; }          // 1, zc, deg2 (x G[0]=1)
    else if (c < 969) {                                          // deg3 = deg2[suffix]*zc[i]
      int t = c - 153, i = 0;
      for (;;) { int cn = (16 - i) * (17 - i) / 2; if (t < cn) break; t -= cn; ++i; }
      goff = (unsigned)(17 + (136 - (16 - i) * (17 - i) / 2) + t);
      midx = (unsigned)(1 + i);
    }
    else              { goff = (unsigned)(153 + (c - 969)); midx = 0; }  // sines
    const unsigned base = (unsigned)(r * GSTR);
    etab[fe] = (base + goff) | ((base + midx) << 16);
  }
  __syncthreads();

  // classify units: normal iff 4 consecutive goff + uniform midx
  for (int u = tid; u < NUNIT; u += 256) {
    const unsigned e0 = etab[4 * u];
    const unsigned g0 = e0 & 0xffffu, m = e0 >> 16;
    const bool normal =
      etab[4 * u + 1] == ((g0 + 1) | (m << 16)) &&
      etab[4 * u + 2] == ((g0 + 2) | (m << 16)) &&
      etab[4 * u + 3] == ((g0 + 3) | (m << 16));
    if (normal) {
      int s = atomicAdd(&cnt[0], 1);
      nlist[s] = make_uint2((unsigned)u, e0);
    } else {
      int s = atomicAdd(&cnt[1], 1);
      if (s < MAXSTR) {
        sdst[s] = (unsigned short)u;
        sel[4 * s + 0] = etab[4 * u + 0];
        sel[4 * s + 1] = etab[4 * u + 1];
        sel[4 * s + 2] = etab[4 * u + 2];
        sel[4 * s + 3] = etab[4 * u + 3];
      }
    }
  }
  __syncthreads();
  const int n_norm = cnt[0];
  const int n_str  = cnt[1];

  uint2 ne[8];                                    // hoist normal-unit entries to VGPRs
  #pragma unroll
  for (int k = 0; k < 8; ++k) {
    const int idx = k * 256 + tid;
    ne[k] = (idx < n_norm) ? nlist[idx] : make_uint2(0u, 0u);
  }
  __syncthreads();   // table reads done; buf reusable as tile storage

  const unsigned pe0 = ptab[l];
  const unsigned pe1 = ptab[64 + l];
  const unsigned pe2 = ptab[(128 + l < 136) ? (128 + l) : 135];

  // ---- stage G for one tile: wave w stages rows 2w, 2w+1 ----
  auto stage_rows = [&](int row0) {
    #pragma unroll
    for (int rr = 0; rr < 2; ++rr) {
      const int lr  = 2 * w + rr;
      const int row = row0 + lr;
      float* Gr = Gsh + lr * GSTR;
      if (row < batch) {
        float gval = 0.f;
        if (l == 0)       gval = 1.0f;
        else if (l < 9)   gval = z [(size_t)row * 8 + (l - 1)];
        else if (l < 17)  gval = dz[(size_t)row * 8 + (l - 9)];
        const int gaddr = (l < 17) ? l : (152 + l);              // zero-pad 169..175
        if (l < 24) Gr[gaddr] = gval;
        const float sv = __shfl(gval, l + 1);
        if (l < 16) Gr[153 + l] = __sinf(sv);
        __builtin_amdgcn_sched_barrier(0);        // base writes before pair gathers
        {
          float a0 = Gr[1 + (pe0 & 15)], b0 = Gr[1 + (pe0 >> 4)];
          Gr[17 + l] = a0 * b0;
          float a1 = Gr[1 + (pe1 & 15)], b1 = Gr[1 + (pe1 >> 4)];
          Gr[17 + 64 + l] = a1 * b1;
          if (l < 8) {
            float a2 = Gr[1 + (pe2 & 15)], b2 = Gr[1 + (pe2 >> 4)];
            Gr[17 + 128 + l] = a2 * b2;
          }
        }
        __builtin_amdgcn_sched_barrier(0);
      }
    }
  };

  // ================= pipeline: [stageG(t)] bar [drain(t-1) ∥ units(t)] bar ====
  int t = blockIdx.x;
  int p = 0;
  int t_prev = -1;
  for (; t < ntiles; t += gridDim.x) {
    stage_rows(t * TROWS);
    __syncthreads();                               // G ready; prev drain stores landed

    float* bw = buf[p];
    const float4* dsrc = (const float4*)buf[p ^ 1];
    float4* __restrict__ dglob =
        (t_prev >= 0) ? (float4*)(out + (size_t)t_prev * TILEF) : (float4*)out;

    #pragma unroll
    for (int k = 0; k < 8; ++k) {
      // drain iter k of previous tile — stores issue early & throughout the phase
      if (t_prev >= 0) {
        const int u = k * 256 + tid;
        if (k < 7 || u < NUNIT) dglob[u] = dsrc[u];
      }
      // normal-unit iter k of current tile: 2x ds_read2 + 1 broadcast + 1 write_b128
      {
        const int idx = k * 256 + tid;
        const unsigned uu = ne[k].x;
        const unsigned g0 = ne[k].y & 0xffffu;
        const unsigned m  = ne[k].y >> 16;
        const float mv = Gsh[m];
        const float a0 = Gsh[g0], a1 = Gsh[g0 + 1], a2 = Gsh[g0 + 2], a3 = Gsh[g0 + 3];
        float4 v; v.x = a0 * mv; v.y = a1 * mv; v.z = a2 * mv; v.w = a3 * mv;
        if (idx < n_norm) *(float4*)&bw[4 * uu] = v;
      }
    }
    // straddle units (~144): per-element entries, one masked pass
    if (tid < n_str) {
      const int uu = sdst[tid];
      const unsigned e0 = sel[4 * tid], e1 = sel[4 * tid + 1];
      const unsigned e2 = sel[4 * tid + 2], e3 = sel[4 * tid + 3];
      float4 v;
      v.x = Gsh[e0 & 0xffffu] * Gsh[e0 >> 16];
      v.y = Gsh[e1 & 0xffffu] * Gsh[e1 >> 16];
      v.z = Gsh[e2 & 0xffffu] * Gsh[e2 >> 16];
      v.w = Gsh[e3 & 0xffffu] * Gsh[e3 >> 16];
      *(float4*)&bw[4 * uu] = v;
    }
    __syncthreads();                               // tile staged; safe to advance
    t_prev = t; p ^= 1;
  }

  // epilogue: drain the block's last computed tile
  if (t_prev >= 0) {
    const float4* dsrc = (const float4*)buf[p ^ 1];
    const int nel = batch * NCOLS - t_prev * TILEF;
    float4* __restrict__ dglob = (float4*)(out + (size_t)t_prev * TILEF);
    if (nel >= TILEF) {
      #pragma unroll
      for (int k = 0; k < 8; ++k) {
        const int u = k * 256 + tid;
        if (k < 7 || u < NUNIT) dglob[u] = dsrc[u];
      }
    } else {
      const float* s = (const float*)dsrc;
      float* d = (float*)dglob;
      for (int u = tid; u < nel; u += 256) d[u] = s[u];
    }
  }
}

extern "C" void kernel_launch(void* const* d_in, const int* in_sizes, int n_in,
                              void* d_out, int out_size, void* d_ws, size_t ws_size,
                              hipStream_t stream) {
  const float* z  = (const float*)d_in[0];
  const float* dz = (const float*)d_in[1];
  float* out = (float*)d_out;
  const int batch = in_sizes[0] / 8;   // LATENT_DIM = 8

  const int ntiles = (batch + TROWS - 1) / TROWS;   // 16384
  const int blocks = 2048;                           // 8 tiles/block; 2 blocks/CU resident
  sindy_kernel<<<blocks, 256, 0, stream>>>(z, dz, out, batch, ntiles);
}